// Round 9
// baseline (539.227 us; speedup 1.0000x reference)
//
#include <hip/hip_runtime.h>
#include <hip/hip_cooperative_groups.h>

namespace cg = cooperative_groups;

// ---------- types / helpers ----------
typedef __attribute__((ext_vector_type(8))) short short8;   // 8 bf16 = 4 VGPRs
typedef __attribute__((ext_vector_type(4))) float f32x4;

__device__ __forceinline__ float bf2f(unsigned short u) {
    union { unsigned int i; float f; } x; x.i = ((unsigned int)u) << 16; return x.f;
}
__device__ __forceinline__ unsigned short f2bf(float f) {
    union { float f; unsigned int i; } x; x.f = f;
    unsigned int r = x.i + 0x7fffu + ((x.i >> 16) & 1u);   // RTNE
    return (unsigned short)(r >> 16);
}
__device__ __forceinline__ void async_copy16(const void* g, void* l) {
    __builtin_amdgcn_global_load_lds(
        (const __attribute__((address_space(1))) void*)g,
        (__attribute__((address_space(3))) void*)l,
        16, 0, 0);
}

// ---------- fused prep: x fp32->bf16 (blocks 0..8191), Wqkv^T (8192..11263),
// ---------- Wout^T (11264..12287).
__global__ __launch_bounds__(256) void prep(const float* __restrict__ x,
                                            const float* __restrict__ Wqkv,
                                            const float* __restrict__ Wout,
                                            unsigned short* __restrict__ x_bf,
                                            unsigned short* __restrict__ WqkvT,
                                            unsigned short* __restrict__ WoutT) {
    __shared__ float tile[32][33];
    const int blk = blockIdx.x;
    if (blk < 8192) {
        const size_t i = ((size_t)blk * 256 + threadIdx.x) * 8;
        float4 v0 = *(const float4*)&x[i];
        float4 v1 = *(const float4*)&x[i + 4];
        short8 o;
        o[0] = (short)f2bf(v0.x); o[1] = (short)f2bf(v0.y);
        o[2] = (short)f2bf(v0.z); o[3] = (short)f2bf(v0.w);
        o[4] = (short)f2bf(v1.x); o[5] = (short)f2bf(v1.y);
        o[6] = (short)f2bf(v1.z); o[7] = (short)f2bf(v1.w);
        *(short8*)&x_bf[i] = o;
        return;
    }
    const float* in;
    unsigned short* out;
    int R, C, idx;
    if (blk < 11264) { in = Wqkv; out = WqkvT; R = 1024; C = 3072; idx = blk - 8192; }
    else             { in = Wout; out = WoutT; R = 1024; C = 1024; idx = blk - 11264; }
    const int nbx = C / 32;
    const int bx = (idx % nbx) * 32;
    const int by = (idx / nbx) * 32;
    const int tx = threadIdx.x & 31, ty = threadIdx.x >> 5;
    #pragma unroll
    for (int r = ty; r < 32; r += 8)
        tile[r][tx] = in[(size_t)(by + r) * C + bx + tx];
    __syncthreads();
    #pragma unroll
    for (int r = ty; r < 32; r += 8)
        out[(size_t)(bx + r) * R + by + tx] = f2bf(tile[tx][r]);
}

// ---------- bf16 GEMM: C[M,N] = A[M,K] * Bt[N,K]^T + bias ----------
// FROZEN (R7): 256x256 tile, BK=64, 512 threads (8 waves 2x4), 4 quadrant
// phases per K-tile {12,4,8,0} ds_reads, staging B1(t+1)@ph1, B0(t+2)@ph2,
// A0(t+2)@ph3, A1(t+2)@ph4, vmcnt(6)@ph4. Epilogues: bf16 LDS-restage (GEMM1),
// fp32 LDS-restage with per-row rq scaling (GEMM2).
template<bool OUT_BF16>
__global__ __launch_bounds__(512, 2) void gemm_bf16(const unsigned short* __restrict__ A, int lda,
                                                    const unsigned short* __restrict__ Bt, int ldb,
                                                    const float* __restrict__ bias,
                                                    const float* __restrict__ rq,
                                                    void* __restrict__ C, int ldc, int K, int ntn,
                                                    int bstride) {
    __shared__ short smem[65536];   // 128 KiB

    const int tid  = threadIdx.x;
    const int lane = tid & 63;
    const int quad = lane >> 4;
    const int l16  = lane & 15;
    const int wid  = tid >> 6;
    const int wm   = wid >> 2;       // 0..1
    const int wn   = wid & 3;        // 0..3

    // XCD-aware bijective blockIdx swizzle (grids are % 8 == 0)
    const int nwg = gridDim.x;
    const int bid = blockIdx.x;
    const int wg  = (bid & 7) * (nwg >> 3) + (bid >> 3);
    const int m0  = (wg / ntn) * 256;
    const int n0  = (wg % ntn) * 256;

    Bt += (size_t)(m0 >> 12) * (size_t)bstride;   // per-batch B panel (0 for GEMM1)

    const int NT = K >> 6;           // K-tiles (16 for K=1024); must be even >= 4

    // ---- hoisted LDS read bases (shorts). Swizzle chunk SW = quad ^ ((l16>>1)&3).
    const int SW8  = (quad ^ ((l16 >> 1) & 3)) * 8;
    const int offA = (wm * 128 + l16) * 32 + SW8;
    const int offB = 16384 + (wn * 64 + l16) * 32 + SW8;
    const short* pA0 = smem + offA;
    const short* pA1 = smem + 32768 + offA;
    const short* pB0 = smem + offB;
    const short* pB1 = smem + 32768 + offB;

    // ---- staging source pointers (advance by 64 shorts per K-tile, 128 per pair)
    const unsigned short *aS0, *aS1, *bS0, *bS1;
    {
        const int L0  = tid,        r0 = L0 >> 2, c0 = (L0 & 3) ^ ((r0 >> 1) & 3);
        const int L1  = 512 + tid,  r1 = L1 >> 2, c1 = (L1 & 3) ^ ((r1 >> 1) & 3);
        aS0 = A  + (size_t)(m0 + r0) * lda + c0 * 8;
        aS1 = A  + (size_t)(m0 + r1) * lda + c1 * 8;
        bS0 = Bt + (size_t)(n0 + r0) * ldb + c0 * 8;
        bS1 = Bt + (size_t)(n0 + r1) * ldb + c1 * 8;
    }
    const int dstoff = tid * 8;      // shorts (lane x 16B, linear gload_lds dest)

#define STAGE(BUF, ISB, H, AH) do { \
        short* d_ = smem + (BUF) * 32768 + (ISB) * 16384 + (H) * 8192 + dstoff; \
        async_copy16(((ISB) ? bS0 : aS0) + (AH) * 64 + (H) * 32, d_); \
        async_copy16(((ISB) ? bS1 : aS1) + (AH) * 64 + (H) * 32, d_ + 4096); \
    } while (0)

#define RDA4(dst, P, H, IB) do { \
        dst[0] = *(const short8*)(pA##P + ((IB) + 0) * 512 + (H) * 8192); \
        dst[1] = *(const short8*)(pA##P + ((IB) + 1) * 512 + (H) * 8192); \
        dst[2] = *(const short8*)(pA##P + ((IB) + 2) * 512 + (H) * 8192); \
        dst[3] = *(const short8*)(pA##P + ((IB) + 3) * 512 + (H) * 8192); \
    } while (0)
#define RDB2(dst, P, H, JB) do { \
        dst[0] = *(const short8*)(pB##P + ((JB) + 0) * 512 + (H) * 8192); \
        dst[1] = *(const short8*)(pB##P + ((JB) + 1) * 512 + (H) * 8192); \
    } while (0)

#define MFMA_Q(IB, JB, ak0, ak1, bk0, bk1) do { \
        _Pragma("unroll") \
        for (int i_ = 0; i_ < 4; i_++) \
            _Pragma("unroll") \
            for (int j_ = 0; j_ < 2; j_++) \
                acc[(IB) + i_][(JB) + j_] = __builtin_amdgcn_mfma_f32_16x16x32_bf16(ak0[i_], bk0[j_], acc[(IB) + i_][(JB) + j_], 0, 0, 0); \
        _Pragma("unroll") \
        for (int i_ = 0; i_ < 4; i_++) \
            _Pragma("unroll") \
            for (int j_ = 0; j_ < 2; j_++) \
                acc[(IB) + i_][(JB) + j_] = __builtin_amdgcn_mfma_f32_16x16x32_bf16(ak1[i_], bk1[j_], acc[(IB) + i_][(JB) + j_], 0, 0, 0); \
    } while (0)

#define PH_MID() do { \
        __builtin_amdgcn_s_barrier(); \
        __builtin_amdgcn_s_setprio(1); \
    } while (0)
#define PH_END() do { \
        __builtin_amdgcn_s_setprio(0); \
        __builtin_amdgcn_s_barrier(); \
    } while (0)

#define VM6   asm volatile("s_waitcnt vmcnt(6)" ::: "memory")
#define VM0   asm volatile("s_waitcnt vmcnt(0)" ::: "memory")
#define VMNOP ((void)0)

#define KTILE(P, AH, T1, T2, VMW) do { \
        short8 a0k0[4], a0k1[4], a1k0[4], a1k1[4]; \
        short8 b0k0[2], b0k1[2], b1k0[2], b1k1[2]; \
        RDA4(a0k0, P, 0, 0); RDA4(a0k1, P, 1, 0); \
        RDB2(b0k0, P, 0, 0); RDB2(b0k1, P, 1, 0); \
        if (T1) STAGE((P) ^ 1, 1, 1, (AH) + 1); \
        PH_MID(); MFMA_Q(0, 0, a0k0, a0k1, b0k0, b0k1); PH_END(); \
        RDB2(b1k0, P, 0, 2); RDB2(b1k1, P, 1, 2); \
        if (T2) STAGE(P, 1, 0, (AH) + 2); \
        PH_MID(); MFMA_Q(0, 2, a0k0, a0k1, b1k0, b1k1); PH_END(); \
        RDA4(a1k0, P, 0, 4); RDA4(a1k1, P, 1, 4); \
        if (T2) STAGE(P, 0, 0, (AH) + 2); \
        PH_MID(); MFMA_Q(4, 2, a1k0, a1k1, b1k0, b1k1); PH_END(); \
        if (T2) STAGE(P, 0, 1, (AH) + 2); \
        VMW; \
        PH_MID(); MFMA_Q(4, 0, a1k0, a1k1, b0k0, b0k1); PH_END(); \
    } while (0)

    f32x4 acc[8][4] = {};

    // ---- prologue: tile0 {A0,B0,A1,B1}; tile1 {B0,A0,A1}
    STAGE(0, 0, 0, 0); STAGE(0, 1, 0, 0); STAGE(0, 0, 1, 0); STAGE(0, 1, 1, 0);
    asm volatile("s_waitcnt vmcnt(4)" ::: "memory");
    STAGE(1, 1, 0, 1); STAGE(1, 0, 0, 1); STAGE(1, 0, 1, 1);
    asm volatile("s_waitcnt vmcnt(6)" ::: "memory");
    __builtin_amdgcn_s_barrier();

    for (int u = 0; u + 3 < NT; u += 2) {
        KTILE(0, 0, 1, 1, VM6);
        KTILE(1, 1, 1, 1, VM6);
        aS0 += 128; aS1 += 128; bS0 += 128; bS1 += 128;
    }
    KTILE(0, 0, 1, 0, VM0);
    KTILE(1, 1, 0, 0, VMNOP);

    // ---- epilogue. C/D layout: col = lane&15, row = quad*4 + r  [m89/m91]
    if (OUT_BF16) {
        __syncthreads();                               // full drain; reuse smem
        unsigned short* tile = (unsigned short*)smem;  // [128][264] padded
        unsigned short* Cp   = (unsigned short*)C;
        #pragma unroll
        for (int hm = 0; hm < 2; hm++) {
            if (wm == hm) {
                #pragma unroll
                for (int j = 0; j < 4; j++) {
                    const int tcol = wn * 64 + j * 16 + l16;
                    const float bv = bias[n0 + tcol];
                    #pragma unroll
                    for (int i = 0; i < 8; i++) {
                        const int trow = i * 16 + quad * 4;
                        #pragma unroll
                        for (int r = 0; r < 4; r++)
                            tile[(trow + r) * 264 + tcol] = f2bf(acc[i][j][r] + bv);
                    }
                }
            }
            __syncthreads();
            #pragma unroll
            for (int pp = 0; pp < 8; pp++) {
                const int row = pp * 16 + (tid >> 5);
                const int ch  = tid & 31;
                short8 v = *(const short8*)&tile[row * 264 + ch * 8];
                *(short8*)&Cp[(size_t)(m0 + hm * 128 + row) * ldc + n0 + ch * 8] = v;
            }
            __syncthreads();
        }
    } else {
        // fp32 out with per-row rq scaling: y = rq[row]*acc + bias, LDS-restaged
        // for 1KiB-contiguous stores. XOR bit-4 swizzle (bijective both sides).
        __syncthreads();
        float* ftile = (float*)smem;
        float* Cp = (float*)C;
        #pragma unroll
        for (int hm = 0; hm < 2; hm++) {
            if (wm == hm) {
                #pragma unroll
                for (int j = 0; j < 4; j++) {
                    const int tcol = wn * 64 + j * 16 + l16;
                    const float bv = bias[n0 + tcol];
                    #pragma unroll
                    for (int i = 0; i < 8; i++) {
                        const int trow = i * 16 + quad * 4;
                        const int cs = tcol ^ ((quad & 1) << 4);
                        #pragma unroll
                        for (int r = 0; r < 4; r++) {
                            const float rqv = rq[m0 + hm * 128 + trow + r];
                            ftile[(trow + r) * 256 + cs] = acc[i][j][r] * rqv + bv;
                        }
                    }
                }
            }
            __syncthreads();
            #pragma unroll
            for (int p = 0; p < 16; p++) {
                const int row = p * 8 + (tid >> 6);
                const int c4  = (tid & 63) * 4;
                const int cr  = c4 ^ (((row >> 2) & 1) << 4);
                float4 v = *(const float4*)&ftile[row * 256 + cr];
                *(float4*)&Cp[(size_t)(m0 + hm * 128 + row) * ldc + n0 + c4] = v;
            }
            __syncthreads();
        }
    }
#undef STAGE
#undef RDA4
#undef RDB2
#undef MFMA_Q
#undef PH_MID
#undef PH_END
#undef VM6
#undef VM0
#undef VMNOP
#undef KTILE
}

// ---------- shared device body: per-row q/k norms + kv partials ----------
__device__ __forceinline__ void norm_body(const unsigned short* __restrict__ qkv,
                                          float* __restrict__ rnq,
                                          float* __restrict__ part,
                                          float kvbuf[4][1024]) {
    const int tid = threadIdx.x, lane = tid & 63, wv = tid >> 6;
    const int row0 = blockIdx.x * 16 + wv * 4;
    float a[2][8] = {};

    #pragma unroll
    for (int rr = 0; rr < 4; rr++) {
        const size_t base = (size_t)(row0 + rr) * 3072;
        float q2 = 0.f;
        #pragma unroll
        for (int c = 0; c < 2; c++) {
            short8 qu = *(const short8*)&qkv[base + c * 512 + lane * 8];
            #pragma unroll
            for (int j = 0; j < 8; j++) {
                float v = bf2f((unsigned short)qu[j]);
                q2 += v * v;
            }
        }
        #pragma unroll
        for (int m = 32; m; m >>= 1) q2 += __shfl_xor(q2, m, 64);
        if (lane == 0) rnq[row0 + rr] = rsqrtf(q2);

        float k2 = 0.f;
        float kf[2][8];
        #pragma unroll
        for (int c = 0; c < 2; c++) {
            short8 ku = *(const short8*)&qkv[base + 1024 + c * 512 + lane * 8];
            #pragma unroll
            for (int j = 0; j < 8; j++) {
                kf[c][j] = bf2f((unsigned short)ku[j]);
                k2 += kf[c][j] * kf[c][j];
            }
        }
        #pragma unroll
        for (int m = 32; m; m >>= 1) k2 += __shfl_xor(k2, m, 64);
        const float rk = rsqrtf(k2);

        #pragma unroll
        for (int c = 0; c < 2; c++) {
            short8 vu = *(const short8*)&qkv[base + 2048 + c * 512 + lane * 8];
            #pragma unroll
            for (int j = 0; j < 8; j++)
                a[c][j] += kf[c][j] * rk * bf2f((unsigned short)vu[j]);
        }
    }
    #pragma unroll
    for (int c = 0; c < 2; c++) {
        *(float4*)&kvbuf[wv][c * 512 + lane * 8]     = make_float4(a[c][0], a[c][1], a[c][2], a[c][3]);
        *(float4*)&kvbuf[wv][c * 512 + lane * 8 + 4] = make_float4(a[c][4], a[c][5], a[c][6], a[c][7]);
    }
    __syncthreads();
    float4 s = *(const float4*)&kvbuf[0][tid * 4];
    #pragma unroll
    for (int w = 1; w < 4; w++) {
        float4 t = *(const float4*)&kvbuf[w][tid * 4];
        s.x += t.x; s.y += t.y; s.z += t.z; s.w += t.w;
    }
    *(float4*)&part[(size_t)blockIdx.x * 1024 + tid * 4] = s;
}

// ---------- cooperative fused: norm -> grid.sync -> reduce -> grid.sync -> scale ----------
// 1024 blocks x 256 thr (exact co-residency: 4 blocks/CU, 64 KB LDS, 16 waves/CU).
__global__ __launch_bounds__(256) void norm_reduce_scale(const unsigned short* __restrict__ qkv,
                                                         float* __restrict__ rnq,
                                                         float* __restrict__ part,
                                                         const unsigned short* __restrict__ WoutT,
                                                         float* __restrict__ kv,
                                                         unsigned short* __restrict__ WoutS) {
    __shared__ float kvbuf[4][1024];   // 16 KB
    norm_body(qkv, rnq, part, kvbuf);

    cg::this_grid().sync();

    // phase 2: kv[b][col] = sum of 256 partials. 1024 blocks x 4 cols each.
    {
        const int lane = threadIdx.x & 63;
        const int b    = blockIdx.x >> 8;                      // 256 blocks per batch
        const int col  = (blockIdx.x & 255) * 4 + (threadIdx.x >> 6);
        float s = 0.f;
        #pragma unroll
        for (int i = 0; i < 4; i++)
            s += part[(size_t)(b * 256 + lane * 4 + i) * 1024 + col];
        #pragma unroll
        for (int m = 32; m; m >>= 1) s += __shfl_xor(s, m, 64);
        if (lane == 0) kv[b * 1024 + col] = s;
    }

    cg::this_grid().sync();

    // phase 3: WoutS[b][n][k] = WoutT[n][k] * kv[b][k].
    // TWO short8 per thread: 524288 total chunks = 2 x 1024 blocks x 256 thr.
    // (R8 bug: single chunk/thread covered only half of WoutS.)
    #pragma unroll
    for (int h = 0; h < 2; h++) {
        const int idx = blockIdx.x * 512 + h * 256 + threadIdx.x;  // [0, 524288)
        const int b   = idx >> 17;                                 // 131072 chunks/batch
        const int rem = idx & 131071;
        const int n   = rem >> 7;                                  // [0, 1024)
        const int k8  = (rem & 127) * 8;
        short8 w = *(const short8*)&WoutT[n * 1024 + k8];
        float4 k0 = *(const float4*)&kv[b * 1024 + k8];
        float4 k1 = *(const float4*)&kv[b * 1024 + k8 + 4];
        short8 o;
        o[0] = (short)f2bf(bf2f((unsigned short)w[0]) * k0.x);
        o[1] = (short)f2bf(bf2f((unsigned short)w[1]) * k0.y);
        o[2] = (short)f2bf(bf2f((unsigned short)w[2]) * k0.z);
        o[3] = (short)f2bf(bf2f((unsigned short)w[3]) * k0.w);
        o[4] = (short)f2bf(bf2f((unsigned short)w[4]) * k1.x);
        o[5] = (short)f2bf(bf2f((unsigned short)w[5]) * k1.y);
        o[6] = (short)f2bf(bf2f((unsigned short)w[6]) * k1.z);
        o[7] = (short)f2bf(bf2f((unsigned short)w[7]) * k1.w);
        *(short8*)&WoutS[((size_t)b << 20) + n * 1024 + k8] = o;
    }
}

// ---------- fallback (non-cooperative) versions, identical to R7 ----------
__global__ __launch_bounds__(256) void norm_kv(const unsigned short* __restrict__ qkv,
                                               float* __restrict__ rnq,
                                               float* __restrict__ part) {
    __shared__ float kvbuf[4][1024];
    norm_body(qkv, rnq, part, kvbuf);
}

__global__ __launch_bounds__(256) void reduce_kv(const float* __restrict__ part,
                                                 float* __restrict__ kv) {
    __shared__ float red[8][32];
    const int b   = blockIdx.x >> 5;
    const int col = (blockIdx.x & 31) * 32 + (threadIdx.x & 31);
    const int g   = threadIdx.x >> 5;
    float s = 0.f;
    #pragma unroll 4
    for (int r = g * 32; r < g * 32 + 32; r++)
        s += part[(size_t)(b * 256 + r) * 1024 + col];
    red[g][threadIdx.x & 31] = s;
    __syncthreads();
    if (g == 0) {
        float t = 0.f;
        #pragma unroll
        for (int w = 0; w < 8; w++) t += red[w][threadIdx.x & 31];
        kv[b * 1024 + col] = t;
    }
}

__global__ __launch_bounds__(256) void scale_w(const unsigned short* __restrict__ WoutT,
                                               const float* __restrict__ kv,
                                               unsigned short* __restrict__ WoutS) {
    const int b   = blockIdx.x >> 9;
    const int idx = (blockIdx.x & 511) * 256 + threadIdx.x;
    const int n   = idx >> 7;
    const int k8  = (idx & 127) * 8;
    short8 w = *(const short8*)&WoutT[n * 1024 + k8];
    float4 k0 = *(const float4*)&kv[b * 1024 + k8];
    float4 k1 = *(const float4*)&kv[b * 1024 + k8 + 4];
    short8 o;
    o[0] = (short)f2bf(bf2f((unsigned short)w[0]) * k0.x);
    o[1] = (short)f2bf(bf2f((unsigned short)w[1]) * k0.y);
    o[2] = (short)f2bf(bf2f((unsigned short)w[2]) * k0.z);
    o[3] = (short)f2bf(bf2f((unsigned short)w[3]) * k0.w);
    o[4] = (short)f2bf(bf2f((unsigned short)w[4]) * k1.x);
    o[5] = (short)f2bf(bf2f((unsigned short)w[5]) * k1.y);
    o[6] = (short)f2bf(bf2f((unsigned short)w[6]) * k1.z);
    o[7] = (short)f2bf(bf2f((unsigned short)w[7]) * k1.w);
    *(short8*)&WoutS[((size_t)b << 20) + n * 1024 + k8] = o;
}

extern "C" void kernel_launch(void* const* d_in, const int* in_sizes, int n_in,
                              void* d_out, int out_size, void* d_ws, size_t ws_size,
                              hipStream_t stream) {
    const float* x    = (const float*)d_in[0];   // (4,4096,1024)
    const float* Wqkv = (const float*)d_in[1];   // (1024,3072)
    const float* bqkv = (const float*)d_in[2];   // (3072)
    const float* Wout = (const float*)d_in[3];   // (1024,1024)
    const float* bout = (const float*)d_in[4];   // (1024)
    float* out = (float*)d_out;                  // (4,4096,1024) fp32

    // workspace layout (~136 MB)
    char* ws = (char*)d_ws;
    unsigned short* x_bf  = (unsigned short*)(ws + 0);           // 32 MB (dead after GEMM1)
    unsigned short* WqkvT = (unsigned short*)(ws + 33554432);    // 6 MB
    unsigned short* WoutT = (unsigned short*)(ws + 39845888);    // 2 MB
    unsigned short* qkv   = (unsigned short*)(ws + 41943040);    // 96 MB
    float* rnq            = (float*)(ws + 142606336);            // 64 KB
    float* kv             = (float*)(ws + 142671872);            // 16 KB
    float* part           = (float*)(ws + 0);                    // 4 MB (x_bf region, dead)
    unsigned short* WoutS = (unsigned short*)(ws + 8388608);     // 8 MB (x_bf region, dead)

    // fused: x conversion + both weight transposes
    prep<<<12288, 256, 0, stream>>>(x, Wqkv, Wout, x_bf, WqkvT, WoutT);

    // qkv = x @ Wqkv + bqkv   (M=16384, N=3072, K=1024) -> bf16; 64x12 = 768 tiles
    gemm_bf16<true><<<768, 512, 0, stream>>>(x_bf, 1024, WqkvT, 1024, bqkv, nullptr,
                                             (void*)qkv, 3072, 1024, 12, 0);

    // fused norm + reduce + scale_w via cooperative launch (2 grid syncs).
    {
        const unsigned short* qkv_c   = qkv;
        const unsigned short* WoutT_c = WoutT;
        void* args[] = {(void*)&qkv_c, (void*)&rnq, (void*)&part,
                        (void*)&WoutT_c, (void*)&kv, (void*)&WoutS};
        hipError_t e = hipLaunchCooperativeKernel((void*)norm_reduce_scale,
                                                  dim3(1024), dim3(256), args, 0, stream);
        if (e != hipSuccess) {
            // fallback: the three proven separate kernels
            norm_kv<<<1024, 256, 0, stream>>>(qkv, rnq, part);
            reduce_kv<<<128, 256, 0, stream>>>(part, kv);
            scale_w<<<2048, 256, 0, stream>>>(WoutT, kv, WoutS);
        }
    }

    // y[b] = rq * (q[b] @ (Wout .* kv[b])) + bout  (M=16384, N=1024, K=1024) -> fp32
    gemm_bf16<false><<<256, 512, 0, stream>>>(qkv, 3072, WoutS, 1024, bout, rnq,
                                              (void*)out, 1024, 1024, 4, 1 << 20);
}

// Round 10
// 309.087 us; speedup vs baseline: 1.7446x; 1.7446x over previous
//
#include <hip/hip_runtime.h>

// ---------- types / helpers ----------
typedef __attribute__((ext_vector_type(8))) short short8;   // 8 bf16 = 4 VGPRs
typedef __attribute__((ext_vector_type(4))) float f32x4;

__device__ __forceinline__ float bf2f(unsigned short u) {
    union { unsigned int i; float f; } x; x.i = ((unsigned int)u) << 16; return x.f;
}
__device__ __forceinline__ unsigned short f2bf(float f) {
    union { float f; unsigned int i; } x; x.f = f;
    unsigned int r = x.i + 0x7fffu + ((x.i >> 16) & 1u);   // RTNE
    return (unsigned short)(r >> 16);
}
__device__ __forceinline__ void async_copy16(const void* g, void* l) {
    __builtin_amdgcn_global_load_lds(
        (const __attribute__((address_space(1))) void*)g,
        (__attribute__((address_space(3))) void*)l,
        16, 0, 0);
}

// ---------- fused prep: x fp32->bf16 (blocks 0..8191), Wqkv^T (8192..11263),
// ---------- Wout^T (11264..12287).
__global__ __launch_bounds__(256) void prep(const float* __restrict__ x,
                                            const float* __restrict__ Wqkv,
                                            const float* __restrict__ Wout,
                                            unsigned short* __restrict__ x_bf,
                                            unsigned short* __restrict__ WqkvT,
                                            unsigned short* __restrict__ WoutT) {
    __shared__ float tile[32][33];
    const int blk = blockIdx.x;
    if (blk < 8192) {
        const size_t i = ((size_t)blk * 256 + threadIdx.x) * 8;
        float4 v0 = *(const float4*)&x[i];
        float4 v1 = *(const float4*)&x[i + 4];
        short8 o;
        o[0] = (short)f2bf(v0.x); o[1] = (short)f2bf(v0.y);
        o[2] = (short)f2bf(v0.z); o[3] = (short)f2bf(v0.w);
        o[4] = (short)f2bf(v1.x); o[5] = (short)f2bf(v1.y);
        o[6] = (short)f2bf(v1.z); o[7] = (short)f2bf(v1.w);
        *(short8*)&x_bf[i] = o;
        return;
    }
    const float* in;
    unsigned short* out;
    int R, C, idx;
    if (blk < 11264) { in = Wqkv; out = WqkvT; R = 1024; C = 3072; idx = blk - 8192; }
    else             { in = Wout; out = WoutT; R = 1024; C = 1024; idx = blk - 11264; }
    const int nbx = C / 32;
    const int bx = (idx % nbx) * 32;
    const int by = (idx / nbx) * 32;
    const int tx = threadIdx.x & 31, ty = threadIdx.x >> 5;
    #pragma unroll
    for (int r = ty; r < 32; r += 8)
        tile[r][tx] = in[(size_t)(by + r) * C + bx + tx];
    __syncthreads();
    #pragma unroll
    for (int r = ty; r < 32; r += 8)
        out[(size_t)(bx + r) * R + by + tx] = f2bf(tile[tx][r]);
}

// ---------- bf16 GEMM: C[M,N] = A[M,K] * Bt[N,K]^T + bias ----------
// FROZEN (R7): 256x256 tile, BK=64, 512 threads (8 waves 2x4), 4 quadrant
// phases per K-tile {12,4,8,0} ds_reads, staging B1(t+1)@ph1, B0(t+2)@ph2,
// A0(t+2)@ph3, A1(t+2)@ph4, vmcnt(6)@ph4. Epilogues: bf16 LDS-restage (GEMM1),
// fp32 LDS-restage with per-row rq scaling (GEMM2).
template<bool OUT_BF16>
__global__ __launch_bounds__(512, 2) void gemm_bf16(const unsigned short* __restrict__ A, int lda,
                                                    const unsigned short* __restrict__ Bt, int ldb,
                                                    const float* __restrict__ bias,
                                                    const float* __restrict__ rq,
                                                    void* __restrict__ C, int ldc, int K, int ntn,
                                                    int bstride) {
    __shared__ short smem[65536];   // 128 KiB

    const int tid  = threadIdx.x;
    const int lane = tid & 63;
    const int quad = lane >> 4;
    const int l16  = lane & 15;
    const int wid  = tid >> 6;
    const int wm   = wid >> 2;       // 0..1
    const int wn   = wid & 3;        // 0..3

    // XCD-aware bijective blockIdx swizzle (grids are % 8 == 0)
    const int nwg = gridDim.x;
    const int bid = blockIdx.x;
    const int wg  = (bid & 7) * (nwg >> 3) + (bid >> 3);
    const int m0  = (wg / ntn) * 256;
    const int n0  = (wg % ntn) * 256;

    Bt += (size_t)(m0 >> 12) * (size_t)bstride;   // per-batch B panel (0 for GEMM1)

    const int NT = K >> 6;           // K-tiles (16 for K=1024); must be even >= 4

    // ---- hoisted LDS read bases (shorts). Swizzle chunk SW = quad ^ ((l16>>1)&3).
    const int SW8  = (quad ^ ((l16 >> 1) & 3)) * 8;
    const int offA = (wm * 128 + l16) * 32 + SW8;
    const int offB = 16384 + (wn * 64 + l16) * 32 + SW8;
    const short* pA0 = smem + offA;
    const short* pA1 = smem + 32768 + offA;
    const short* pB0 = smem + offB;
    const short* pB1 = smem + 32768 + offB;

    // ---- staging source pointers (advance by 64 shorts per K-tile, 128 per pair)
    const unsigned short *aS0, *aS1, *bS0, *bS1;
    {
        const int L0  = tid,        r0 = L0 >> 2, c0 = (L0 & 3) ^ ((r0 >> 1) & 3);
        const int L1  = 512 + tid,  r1 = L1 >> 2, c1 = (L1 & 3) ^ ((r1 >> 1) & 3);
        aS0 = A  + (size_t)(m0 + r0) * lda + c0 * 8;
        aS1 = A  + (size_t)(m0 + r1) * lda + c1 * 8;
        bS0 = Bt + (size_t)(n0 + r0) * ldb + c0 * 8;
        bS1 = Bt + (size_t)(n0 + r1) * ldb + c1 * 8;
    }
    const int dstoff = tid * 8;      // shorts (lane x 16B, linear gload_lds dest)

#define STAGE(BUF, ISB, H, AH) do { \
        short* d_ = smem + (BUF) * 32768 + (ISB) * 16384 + (H) * 8192 + dstoff; \
        async_copy16(((ISB) ? bS0 : aS0) + (AH) * 64 + (H) * 32, d_); \
        async_copy16(((ISB) ? bS1 : aS1) + (AH) * 64 + (H) * 32, d_ + 4096); \
    } while (0)

#define RDA4(dst, P, H, IB) do { \
        dst[0] = *(const short8*)(pA##P + ((IB) + 0) * 512 + (H) * 8192); \
        dst[1] = *(const short8*)(pA##P + ((IB) + 1) * 512 + (H) * 8192); \
        dst[2] = *(const short8*)(pA##P + ((IB) + 2) * 512 + (H) * 8192); \
        dst[3] = *(const short8*)(pA##P + ((IB) + 3) * 512 + (H) * 8192); \
    } while (0)
#define RDB2(dst, P, H, JB) do { \
        dst[0] = *(const short8*)(pB##P + ((JB) + 0) * 512 + (H) * 8192); \
        dst[1] = *(const short8*)(pB##P + ((JB) + 1) * 512 + (H) * 8192); \
    } while (0)

#define MFMA_Q(IB, JB, ak0, ak1, bk0, bk1) do { \
        _Pragma("unroll") \
        for (int i_ = 0; i_ < 4; i_++) \
            _Pragma("unroll") \
            for (int j_ = 0; j_ < 2; j_++) \
                acc[(IB) + i_][(JB) + j_] = __builtin_amdgcn_mfma_f32_16x16x32_bf16(ak0[i_], bk0[j_], acc[(IB) + i_][(JB) + j_], 0, 0, 0); \
        _Pragma("unroll") \
        for (int i_ = 0; i_ < 4; i_++) \
            _Pragma("unroll") \
            for (int j_ = 0; j_ < 2; j_++) \
                acc[(IB) + i_][(JB) + j_] = __builtin_amdgcn_mfma_f32_16x16x32_bf16(ak1[i_], bk1[j_], acc[(IB) + i_][(JB) + j_], 0, 0, 0); \
    } while (0)

#define PH_MID() do { \
        __builtin_amdgcn_s_barrier(); \
        __builtin_amdgcn_s_setprio(1); \
    } while (0)
#define PH_END() do { \
        __builtin_amdgcn_s_setprio(0); \
        __builtin_amdgcn_s_barrier(); \
    } while (0)

#define VM6   asm volatile("s_waitcnt vmcnt(6)" ::: "memory")
#define VM0   asm volatile("s_waitcnt vmcnt(0)" ::: "memory")
#define VMNOP ((void)0)

#define KTILE(P, AH, T1, T2, VMW) do { \
        short8 a0k0[4], a0k1[4], a1k0[4], a1k1[4]; \
        short8 b0k0[2], b0k1[2], b1k0[2], b1k1[2]; \
        RDA4(a0k0, P, 0, 0); RDA4(a0k1, P, 1, 0); \
        RDB2(b0k0, P, 0, 0); RDB2(b0k1, P, 1, 0); \
        if (T1) STAGE((P) ^ 1, 1, 1, (AH) + 1); \
        PH_MID(); MFMA_Q(0, 0, a0k0, a0k1, b0k0, b0k1); PH_END(); \
        RDB2(b1k0, P, 0, 2); RDB2(b1k1, P, 1, 2); \
        if (T2) STAGE(P, 1, 0, (AH) + 2); \
        PH_MID(); MFMA_Q(0, 2, a0k0, a0k1, b1k0, b1k1); PH_END(); \
        RDA4(a1k0, P, 0, 4); RDA4(a1k1, P, 1, 4); \
        if (T2) STAGE(P, 0, 0, (AH) + 2); \
        PH_MID(); MFMA_Q(4, 2, a1k0, a1k1, b1k0, b1k1); PH_END(); \
        if (T2) STAGE(P, 0, 1, (AH) + 2); \
        VMW; \
        PH_MID(); MFMA_Q(4, 0, a1k0, a1k1, b0k0, b0k1); PH_END(); \
    } while (0)

    f32x4 acc[8][4] = {};

    // ---- prologue: tile0 {A0,B0,A1,B1}; tile1 {B0,A0,A1}
    STAGE(0, 0, 0, 0); STAGE(0, 1, 0, 0); STAGE(0, 0, 1, 0); STAGE(0, 1, 1, 0);
    asm volatile("s_waitcnt vmcnt(4)" ::: "memory");
    STAGE(1, 1, 0, 1); STAGE(1, 0, 0, 1); STAGE(1, 0, 1, 1);
    asm volatile("s_waitcnt vmcnt(6)" ::: "memory");
    __builtin_amdgcn_s_barrier();

    for (int u = 0; u + 3 < NT; u += 2) {
        KTILE(0, 0, 1, 1, VM6);
        KTILE(1, 1, 1, 1, VM6);
        aS0 += 128; aS1 += 128; bS0 += 128; bS1 += 128;
    }
    KTILE(0, 0, 1, 0, VM0);
    KTILE(1, 1, 0, 0, VMNOP);

    // ---- epilogue. C/D layout: col = lane&15, row = quad*4 + r  [m89/m91]
    if (OUT_BF16) {
        __syncthreads();                               // full drain; reuse smem
        unsigned short* tile = (unsigned short*)smem;  // [128][264] padded
        unsigned short* Cp   = (unsigned short*)C;
        #pragma unroll
        for (int hm = 0; hm < 2; hm++) {
            if (wm == hm) {
                #pragma unroll
                for (int j = 0; j < 4; j++) {
                    const int tcol = wn * 64 + j * 16 + l16;
                    const float bv = bias[n0 + tcol];
                    #pragma unroll
                    for (int i = 0; i < 8; i++) {
                        const int trow = i * 16 + quad * 4;
                        #pragma unroll
                        for (int r = 0; r < 4; r++)
                            tile[(trow + r) * 264 + tcol] = f2bf(acc[i][j][r] + bv);
                    }
                }
            }
            __syncthreads();
            #pragma unroll
            for (int pp = 0; pp < 8; pp++) {
                const int row = pp * 16 + (tid >> 5);
                const int ch  = tid & 31;
                short8 v = *(const short8*)&tile[row * 264 + ch * 8];
                *(short8*)&Cp[(size_t)(m0 + hm * 128 + row) * ldc + n0 + ch * 8] = v;
            }
            __syncthreads();
        }
    } else {
        // fp32 out with per-row rq scaling: y = rq[row]*acc + bias, LDS-restaged
        // for 1KiB-contiguous stores. XOR bit-4 swizzle (bijective both sides).
        __syncthreads();
        float* ftile = (float*)smem;
        float* Cp = (float*)C;
        #pragma unroll
        for (int hm = 0; hm < 2; hm++) {
            if (wm == hm) {
                #pragma unroll
                for (int j = 0; j < 4; j++) {
                    const int tcol = wn * 64 + j * 16 + l16;
                    const float bv = bias[n0 + tcol];
                    #pragma unroll
                    for (int i = 0; i < 8; i++) {
                        const int trow = i * 16 + quad * 4;
                        const int cs = tcol ^ ((quad & 1) << 4);
                        #pragma unroll
                        for (int r = 0; r < 4; r++) {
                            const float rqv = rq[m0 + hm * 128 + trow + r];
                            ftile[(trow + r) * 256 + cs] = acc[i][j][r] * rqv + bv;
                        }
                    }
                }
            }
            __syncthreads();
            #pragma unroll
            for (int p = 0; p < 16; p++) {
                const int row = p * 8 + (tid >> 6);
                const int c4  = (tid & 63) * 4;
                const int cr  = c4 ^ (((row >> 2) & 1) << 4);
                float4 v = *(const float4*)&ftile[row * 256 + cr];
                *(float4*)&Cp[(size_t)(m0 + hm * 128 + row) * ldc + n0 + c4] = v;
            }
            __syncthreads();
        }
    }
#undef STAGE
#undef RDA4
#undef RDB2
#undef MFMA_Q
#undef PH_MID
#undef PH_END
#undef VM6
#undef VM0
#undef VMNOP
#undef KTILE
}

// ---------- per-row q/k norms + kv partials (NO atomics, no grid sync) ----------
__global__ __launch_bounds__(256) void norm_kv(const unsigned short* __restrict__ qkv,
                                               float* __restrict__ rnq,
                                               float* __restrict__ part) {
    __shared__ float kvbuf[4][1024];   // 16 KB, one slice per wave
    const int tid = threadIdx.x, lane = tid & 63, wv = tid >> 6;
    const int row0 = blockIdx.x * 16 + wv * 4;
    float a[2][8] = {};

    #pragma unroll
    for (int rr = 0; rr < 4; rr++) {
        const size_t base = (size_t)(row0 + rr) * 3072;
        float q2 = 0.f;
        #pragma unroll
        for (int c = 0; c < 2; c++) {
            short8 qu = *(const short8*)&qkv[base + c * 512 + lane * 8];
            #pragma unroll
            for (int j = 0; j < 8; j++) {
                float v = bf2f((unsigned short)qu[j]);
                q2 += v * v;
            }
        }
        #pragma unroll
        for (int m = 32; m; m >>= 1) q2 += __shfl_xor(q2, m, 64);
        if (lane == 0) rnq[row0 + rr] = rsqrtf(q2);

        float k2 = 0.f;
        float kf[2][8];
        #pragma unroll
        for (int c = 0; c < 2; c++) {
            short8 ku = *(const short8*)&qkv[base + 1024 + c * 512 + lane * 8];
            #pragma unroll
            for (int j = 0; j < 8; j++) {
                kf[c][j] = bf2f((unsigned short)ku[j]);
                k2 += kf[c][j] * kf[c][j];
            }
        }
        #pragma unroll
        for (int m = 32; m; m >>= 1) k2 += __shfl_xor(k2, m, 64);
        const float rk = rsqrtf(k2);

        #pragma unroll
        for (int c = 0; c < 2; c++) {
            short8 vu = *(const short8*)&qkv[base + 2048 + c * 512 + lane * 8];
            #pragma unroll
            for (int j = 0; j < 8; j++)
                a[c][j] += kf[c][j] * rk * bf2f((unsigned short)vu[j]);
        }
    }
    #pragma unroll
    for (int c = 0; c < 2; c++) {
        *(float4*)&kvbuf[wv][c * 512 + lane * 8]     = make_float4(a[c][0], a[c][1], a[c][2], a[c][3]);
        *(float4*)&kvbuf[wv][c * 512 + lane * 8 + 4] = make_float4(a[c][4], a[c][5], a[c][6], a[c][7]);
    }
    __syncthreads();
    float4 s = *(const float4*)&kvbuf[0][tid * 4];
    #pragma unroll
    for (int w = 1; w < 4; w++) {
        float4 t = *(const float4*)&kvbuf[w][tid * 4];
        s.x += t.x; s.y += t.y; s.z += t.z; s.w += t.w;
    }
    *(float4*)&part[(size_t)blockIdx.x * 1024 + tid * 4] = s;
}

// ---------- fused reduce + scale_w (NO cross-block dependency) ----------
// 128 blocks: b = bid>>5, 32 k-cols kc0 = (bid&31)*32. Phase A: reduce the
// 256 partials for those 32 columns into LDS (exact R7 reduce_kv pattern).
// Phase B: since scale_w's k-index equals the reduced column, this block can
// write WoutS[b][n][kc0..kc0+32) for ALL 1024 n rows directly — kv never
// round-trips through global, and the separate scale_w launch disappears.
__global__ __launch_bounds__(256) void reduce_scale(const float* __restrict__ part,
                                                    const unsigned short* __restrict__ WoutT,
                                                    unsigned short* __restrict__ WoutS) {
    __shared__ float red[8][32];
    __shared__ float kvs[32];
    const int b   = blockIdx.x >> 5;
    const int kc0 = (blockIdx.x & 31) * 32;
    const int col = kc0 + (threadIdx.x & 31);
    const int g   = threadIdx.x >> 5;    // 0..7
    float s = 0.f;
    #pragma unroll 4
    for (int r = g * 32; r < g * 32 + 32; r++)
        s += part[(size_t)(b * 256 + r) * 1024 + col];
    red[g][threadIdx.x & 31] = s;
    __syncthreads();
    if (g == 0) {
        float t = 0.f;
        #pragma unroll
        for (int w = 0; w < 8; w++) t += red[w][threadIdx.x & 31];
        kvs[threadIdx.x & 31] = t;
    }
    __syncthreads();

    // Phase B: thread covers kh = (tid&3)*8 (8 shorts), n = (tid>>2) + i*64.
    const int kh = (threadIdx.x & 3) * 8;
    float kvv[8];
    #pragma unroll
    for (int q = 0; q < 8; q++) kvv[q] = kvs[kh + q];
    const unsigned short* src = WoutT + kc0 + kh;
    unsigned short* dst = WoutS + ((size_t)b << 20) + kc0 + kh;
    #pragma unroll
    for (int i = 0; i < 16; i++) {
        const int n = (threadIdx.x >> 2) + i * 64;
        short8 w = *(const short8*)&src[n * 1024];
        short8 o;
        #pragma unroll
        for (int q = 0; q < 8; q++)
            o[q] = (short)f2bf(bf2f((unsigned short)w[q]) * kvv[q]);
        *(short8*)&dst[n * 1024] = o;
    }
}

extern "C" void kernel_launch(void* const* d_in, const int* in_sizes, int n_in,
                              void* d_out, int out_size, void* d_ws, size_t ws_size,
                              hipStream_t stream) {
    const float* x    = (const float*)d_in[0];   // (4,4096,1024)
    const float* Wqkv = (const float*)d_in[1];   // (1024,3072)
    const float* bqkv = (const float*)d_in[2];   // (3072)
    const float* Wout = (const float*)d_in[3];   // (1024,1024)
    const float* bout = (const float*)d_in[4];   // (1024)
    float* out = (float*)d_out;                  // (4,4096,1024) fp32

    // workspace layout (~136 MB)
    char* ws = (char*)d_ws;
    unsigned short* x_bf  = (unsigned short*)(ws + 0);           // 32 MB (dead after GEMM1)
    unsigned short* WqkvT = (unsigned short*)(ws + 33554432);    // 6 MB
    unsigned short* WoutT = (unsigned short*)(ws + 39845888);    // 2 MB
    unsigned short* qkv   = (unsigned short*)(ws + 41943040);    // 96 MB
    float* rnq            = (float*)(ws + 142606336);            // 64 KB
    float* part           = (float*)(ws + 0);                    // 4 MB (x_bf region, dead)
    unsigned short* WoutS = (unsigned short*)(ws + 8388608);     // 8 MB (x_bf region, dead)

    // fused: x conversion + both weight transposes
    prep<<<12288, 256, 0, stream>>>(x, Wqkv, Wout, x_bf, WqkvT, WoutT);

    // qkv = x @ Wqkv + bqkv   (M=16384, N=3072, K=1024) -> bf16; 64x12 = 768 tiles
    gemm_bf16<true><<<768, 512, 0, stream>>>(x_bf, 1024, WqkvT, 1024, bqkv, nullptr,
                                             (void*)qkv, 3072, 1024, 12, 0);

    norm_kv<<<1024, 256, 0, stream>>>(qkv, rnq, part);

    // fold kv into Wout per batch (reduce + scale in one launch, no sync needed)
    reduce_scale<<<128, 256, 0, stream>>>(part, WoutT, WoutS);

    // y[b] = rq * (q[b] @ (Wout .* kv[b])) + bout  (M=16384, N=1024, K=1024) -> fp32
    gemm_bf16<false><<<256, 512, 0, stream>>>(qkv, 3072, WoutS, 1024, bout, rnq,
                                              (void*)out, 1024, 1024, 4, 1 << 20);
}

// Round 11
// 308.240 us; speedup vs baseline: 1.7494x; 1.0027x over previous
//
#include <hip/hip_runtime.h>

// ---------- types / helpers ----------
typedef __attribute__((ext_vector_type(8))) short short8;   // 8 bf16 = 4 VGPRs
typedef __attribute__((ext_vector_type(4))) float f32x4;

__device__ __forceinline__ float bf2f(unsigned short u) {
    union { unsigned int i; float f; } x; x.i = ((unsigned int)u) << 16; return x.f;
}
__device__ __forceinline__ unsigned short f2bf(float f) {
    union { float f; unsigned int i; } x; x.f = f;
    unsigned int r = x.i + 0x7fffu + ((x.i >> 16) & 1u);   // RTNE
    return (unsigned short)(r >> 16);
}
__device__ __forceinline__ void async_copy16(const void* g, void* l) {
    __builtin_amdgcn_global_load_lds(
        (const __attribute__((address_space(1))) void*)g,
        (__attribute__((address_space(3))) void*)l,
        16, 0, 0);
}

// ---------- fused prep: x fp32->bf16 (blocks 0..8191), Wqkv^T (8192..11263),
// ---------- Wout^T (11264..12287).
__global__ __launch_bounds__(256) void prep(const float* __restrict__ x,
                                            const float* __restrict__ Wqkv,
                                            const float* __restrict__ Wout,
                                            unsigned short* __restrict__ x_bf,
                                            unsigned short* __restrict__ WqkvT,
                                            unsigned short* __restrict__ WoutT) {
    __shared__ float tile[32][33];
    const int blk = blockIdx.x;
    if (blk < 8192) {
        const size_t i = ((size_t)blk * 256 + threadIdx.x) * 8;
        float4 v0 = *(const float4*)&x[i];
        float4 v1 = *(const float4*)&x[i + 4];
        short8 o;
        o[0] = (short)f2bf(v0.x); o[1] = (short)f2bf(v0.y);
        o[2] = (short)f2bf(v0.z); o[3] = (short)f2bf(v0.w);
        o[4] = (short)f2bf(v1.x); o[5] = (short)f2bf(v1.y);
        o[6] = (short)f2bf(v1.z); o[7] = (short)f2bf(v1.w);
        *(short8*)&x_bf[i] = o;
        return;
    }
    const float* in;
    unsigned short* out;
    int R, C, idx;
    if (blk < 11264) { in = Wqkv; out = WqkvT; R = 1024; C = 3072; idx = blk - 8192; }
    else             { in = Wout; out = WoutT; R = 1024; C = 1024; idx = blk - 11264; }
    const int nbx = C / 32;
    const int bx = (idx % nbx) * 32;
    const int by = (idx / nbx) * 32;
    const int tx = threadIdx.x & 31, ty = threadIdx.x >> 5;
    #pragma unroll
    for (int r = ty; r < 32; r += 8)
        tile[r][tx] = in[(size_t)(by + r) * C + bx + tx];
    __syncthreads();
    #pragma unroll
    for (int r = ty; r < 32; r += 8)
        out[(size_t)(bx + r) * R + by + tx] = f2bf(tile[tx][r]);
}

// ---------- bf16 GEMM: C[M,N] = A[M,K] * Bt[N,K]^T + bias ----------
// K-loop FROZEN (R4/R7): 256x256 tile, BK=64, 512 threads (8 waves 2x4),
// quadrant phases {12,4,8,0} ds_reads, vmcnt(6)@ph4.
// Round-11 changes:
//  (a) GEMM1 (ntn==12): XCD L2 grouping remapped to 16m x 6n per XCD so the
//      B working set (3 MB) is L2-resident (was 8m x 12n -> 6 MB thrash).
//  (b) GEMM1 epilogue: q-region blocks (n0<1024) compute per-row sum-of-squares
//      of the (rounded) q values via 32-lane shfl reduce + one fp32 atomicAdd
//      per row into q2out -> norm_kv no longer reads q at all.
//  (c) GEMM2 epilogue: rqv = rsqrtf(q2[row]) (rnq buffer eliminated).
template<bool OUT_BF16>
__global__ __launch_bounds__(512, 2) void gemm_bf16(const unsigned short* __restrict__ A, int lda,
                                                    const unsigned short* __restrict__ Bt, int ldb,
                                                    const float* __restrict__ bias,
                                                    const float* __restrict__ rq,
                                                    float* __restrict__ q2out,
                                                    void* __restrict__ C, int ldc, int K, int ntn,
                                                    int bstride) {
    __shared__ short smem[65536];   // 128 KiB

    const int tid  = threadIdx.x;
    const int lane = tid & 63;
    const int quad = lane >> 4;
    const int l16  = lane & 15;
    const int wid  = tid >> 6;
    const int wm   = wid >> 2;       // 0..1
    const int wn   = wid & 3;        // 0..3

    // XCD-aware block swizzle. GEMM1 (ntn==12): each XCD owns a 16m x 6n
    // tile-group (B set 3 MB -> L2-resident). Else: bijective m-major grouping.
    const int bid = blockIdx.x;
    int m0, n0;
    if (ntn == 12) {
        const int i  = bid >> 3;                       // [0,96) within XCD
        m0 = (((bid >> 1) & 3) * 16 + i / 6) * 256;    // (xcd>>1)*16 + im
        n0 = ((bid & 1) * 6 + i % 6) * 256;            // (xcd&1)*6 + in
    } else {
        const int nwg = gridDim.x;
        const int wg  = (bid & 7) * (nwg >> 3) + (bid >> 3);
        m0 = (wg / ntn) * 256;
        n0 = (wg % ntn) * 256;
    }

    Bt += (size_t)(m0 >> 12) * (size_t)bstride;   // per-batch B panel (0 for GEMM1)

    const int NT = K >> 6;           // K-tiles (16 for K=1024); must be even >= 4

    // ---- hoisted LDS read bases (shorts). Swizzle chunk SW = quad ^ ((l16>>1)&3).
    const int SW8  = (quad ^ ((l16 >> 1) & 3)) * 8;
    const int offA = (wm * 128 + l16) * 32 + SW8;
    const int offB = 16384 + (wn * 64 + l16) * 32 + SW8;
    const short* pA0 = smem + offA;
    const short* pA1 = smem + 32768 + offA;
    const short* pB0 = smem + offB;
    const short* pB1 = smem + 32768 + offB;

    // ---- staging source pointers (advance by 64 shorts per K-tile, 128 per pair)
    const unsigned short *aS0, *aS1, *bS0, *bS1;
    {
        const int L0  = tid,        r0 = L0 >> 2, c0 = (L0 & 3) ^ ((r0 >> 1) & 3);
        const int L1  = 512 + tid,  r1 = L1 >> 2, c1 = (L1 & 3) ^ ((r1 >> 1) & 3);
        aS0 = A  + (size_t)(m0 + r0) * lda + c0 * 8;
        aS1 = A  + (size_t)(m0 + r1) * lda + c1 * 8;
        bS0 = Bt + (size_t)(n0 + r0) * ldb + c0 * 8;
        bS1 = Bt + (size_t)(n0 + r1) * ldb + c1 * 8;
    }
    const int dstoff = tid * 8;      // shorts (lane x 16B, linear gload_lds dest)

#define STAGE(BUF, ISB, H, AH) do { \
        short* d_ = smem + (BUF) * 32768 + (ISB) * 16384 + (H) * 8192 + dstoff; \
        async_copy16(((ISB) ? bS0 : aS0) + (AH) * 64 + (H) * 32, d_); \
        async_copy16(((ISB) ? bS1 : aS1) + (AH) * 64 + (H) * 32, d_ + 4096); \
    } while (0)

#define RDA4(dst, P, H, IB) do { \
        dst[0] = *(const short8*)(pA##P + ((IB) + 0) * 512 + (H) * 8192); \
        dst[1] = *(const short8*)(pA##P + ((IB) + 1) * 512 + (H) * 8192); \
        dst[2] = *(const short8*)(pA##P + ((IB) + 2) * 512 + (H) * 8192); \
        dst[3] = *(const short8*)(pA##P + ((IB) + 3) * 512 + (H) * 8192); \
    } while (0)
#define RDB2(dst, P, H, JB) do { \
        dst[0] = *(const short8*)(pB##P + ((JB) + 0) * 512 + (H) * 8192); \
        dst[1] = *(const short8*)(pB##P + ((JB) + 1) * 512 + (H) * 8192); \
    } while (0)

#define MFMA_Q(IB, JB, ak0, ak1, bk0, bk1) do { \
        _Pragma("unroll") \
        for (int i_ = 0; i_ < 4; i_++) \
            _Pragma("unroll") \
            for (int j_ = 0; j_ < 2; j_++) \
                acc[(IB) + i_][(JB) + j_] = __builtin_amdgcn_mfma_f32_16x16x32_bf16(ak0[i_], bk0[j_], acc[(IB) + i_][(JB) + j_], 0, 0, 0); \
        _Pragma("unroll") \
        for (int i_ = 0; i_ < 4; i_++) \
            _Pragma("unroll") \
            for (int j_ = 0; j_ < 2; j_++) \
                acc[(IB) + i_][(JB) + j_] = __builtin_amdgcn_mfma_f32_16x16x32_bf16(ak1[i_], bk1[j_], acc[(IB) + i_][(JB) + j_], 0, 0, 0); \
    } while (0)

#define PH_MID() do { \
        __builtin_amdgcn_s_barrier(); \
        __builtin_amdgcn_s_setprio(1); \
    } while (0)
#define PH_END() do { \
        __builtin_amdgcn_s_setprio(0); \
        __builtin_amdgcn_s_barrier(); \
    } while (0)

#define VM6   asm volatile("s_waitcnt vmcnt(6)" ::: "memory")
#define VM0   asm volatile("s_waitcnt vmcnt(0)" ::: "memory")
#define VMNOP ((void)0)

#define KTILE(P, AH, T1, T2, VMW) do { \
        short8 a0k0[4], a0k1[4], a1k0[4], a1k1[4]; \
        short8 b0k0[2], b0k1[2], b1k0[2], b1k1[2]; \
        RDA4(a0k0, P, 0, 0); RDA4(a0k1, P, 1, 0); \
        RDB2(b0k0, P, 0, 0); RDB2(b0k1, P, 1, 0); \
        if (T1) STAGE((P) ^ 1, 1, 1, (AH) + 1); \
        PH_MID(); MFMA_Q(0, 0, a0k0, a0k1, b0k0, b0k1); PH_END(); \
        RDB2(b1k0, P, 0, 2); RDB2(b1k1, P, 1, 2); \
        if (T2) STAGE(P, 1, 0, (AH) + 2); \
        PH_MID(); MFMA_Q(0, 2, a0k0, a0k1, b1k0, b1k1); PH_END(); \
        RDA4(a1k0, P, 0, 4); RDA4(a1k1, P, 1, 4); \
        if (T2) STAGE(P, 0, 0, (AH) + 2); \
        PH_MID(); MFMA_Q(4, 2, a1k0, a1k1, b1k0, b1k1); PH_END(); \
        if (T2) STAGE(P, 0, 1, (AH) + 2); \
        VMW; \
        PH_MID(); MFMA_Q(4, 0, a1k0, a1k1, b0k0, b0k1); PH_END(); \
    } while (0)

    f32x4 acc[8][4] = {};

    // ---- prologue: tile0 {A0,B0,A1,B1}; tile1 {B0,A0,A1}
    STAGE(0, 0, 0, 0); STAGE(0, 1, 0, 0); STAGE(0, 0, 1, 0); STAGE(0, 1, 1, 0);
    asm volatile("s_waitcnt vmcnt(4)" ::: "memory");
    STAGE(1, 1, 0, 1); STAGE(1, 0, 0, 1); STAGE(1, 0, 1, 1);
    asm volatile("s_waitcnt vmcnt(6)" ::: "memory");
    __builtin_amdgcn_s_barrier();

    for (int u = 0; u + 3 < NT; u += 2) {
        KTILE(0, 0, 1, 1, VM6);
        KTILE(1, 1, 1, 1, VM6);
        aS0 += 128; aS1 += 128; bS0 += 128; bS1 += 128;
    }
    KTILE(0, 0, 1, 0, VM0);
    KTILE(1, 1, 0, 0, VMNOP);

    // ---- epilogue. C/D layout: col = lane&15, row = quad*4 + r  [m89/m91]
    if (OUT_BF16) {
        const bool doq2 = (q2out != nullptr) && (n0 < 1024);   // q-region blocks
        __syncthreads();                               // full drain; reuse smem
        unsigned short* tile = (unsigned short*)smem;  // [128][264] padded
        unsigned short* Cp   = (unsigned short*)C;
        #pragma unroll
        for (int hm = 0; hm < 2; hm++) {
            if (wm == hm) {
                #pragma unroll
                for (int j = 0; j < 4; j++) {
                    const int tcol = wn * 64 + j * 16 + l16;
                    const float bv = bias[n0 + tcol];
                    #pragma unroll
                    for (int i = 0; i < 8; i++) {
                        const int trow = i * 16 + quad * 4;
                        #pragma unroll
                        for (int r = 0; r < 4; r++)
                            tile[(trow + r) * 264 + tcol] = f2bf(acc[i][j][r] + bv);
                    }
                }
            }
            __syncthreads();
            #pragma unroll
            for (int pp = 0; pp < 8; pp++) {
                const int row = pp * 16 + (tid >> 5);
                const int ch  = tid & 31;
                short8 v = *(const short8*)&tile[row * 264 + ch * 8];
                *(short8*)&Cp[(size_t)(m0 + row + hm * 128) * ldc + n0 + ch * 8] = v;
                if (doq2) {
                    // per-row sum of squares of the ROUNDED q values (matches
                    // norm_kv's previous numerics: it read the bf16 qkv).
                    float sq = 0.f;
                    #pragma unroll
                    for (int q = 0; q < 8; q++) {
                        float f = bf2f((unsigned short)v[q]);
                        sq += f * f;
                    }
                    #pragma unroll
                    for (int m = 1; m <= 16; m <<= 1) sq += __shfl_xor(sq, m, 64);
                    if (ch == 0) atomicAdd(&q2out[m0 + hm * 128 + row], sq);
                }
            }
            __syncthreads();
        }
    } else {
        // fp32 out: y = rsqrt(q2[row])*acc + bias, LDS-restaged for 1KiB stores.
        __syncthreads();
        float* ftile = (float*)smem;
        float* Cp = (float*)C;
        #pragma unroll
        for (int hm = 0; hm < 2; hm++) {
            if (wm == hm) {
                #pragma unroll
                for (int j = 0; j < 4; j++) {
                    const int tcol = wn * 64 + j * 16 + l16;
                    const float bv = bias[n0 + tcol];
                    #pragma unroll
                    for (int i = 0; i < 8; i++) {
                        const int trow = i * 16 + quad * 4;
                        const int cs = tcol ^ ((quad & 1) << 4);
                        #pragma unroll
                        for (int r = 0; r < 4; r++) {
                            const float rqv = rsqrtf(rq[m0 + hm * 128 + trow + r]);
                            ftile[(trow + r) * 256 + cs] = acc[i][j][r] * rqv + bv;
                        }
                    }
                }
            }
            __syncthreads();
            #pragma unroll
            for (int p = 0; p < 16; p++) {
                const int row = p * 8 + (tid >> 6);
                const int c4  = (tid & 63) * 4;
                const int cr  = c4 ^ (((row >> 2) & 1) << 4);
                float4 v = *(const float4*)&ftile[row * 256 + cr];
                *(float4*)&Cp[(size_t)(m0 + hm * 128 + row) * ldc + n0 + c4] = v;
            }
            __syncthreads();
        }
    }
#undef STAGE
#undef RDA4
#undef RDB2
#undef MFMA_Q
#undef PH_MID
#undef PH_END
#undef VM6
#undef VM0
#undef VMNOP
#undef KTILE
}

// ---------- k-norm + kv partials (q handled in GEMM1 epilogue now) ----------
__global__ __launch_bounds__(256) void norm_kv(const unsigned short* __restrict__ qkv,
                                               float* __restrict__ part) {
    __shared__ float kvbuf[4][1024];   // 16 KB, one slice per wave
    const int tid = threadIdx.x, lane = tid & 63, wv = tid >> 6;
    const int row0 = blockIdx.x * 16 + wv * 4;
    float a[2][8] = {};

    #pragma unroll
    for (int rr = 0; rr < 4; rr++) {
        const size_t base = (size_t)(row0 + rr) * 3072;
        float k2 = 0.f;
        float kf[2][8];
        #pragma unroll
        for (int c = 0; c < 2; c++) {
            short8 ku = *(const short8*)&qkv[base + 1024 + c * 512 + lane * 8];
            #pragma unroll
            for (int j = 0; j < 8; j++) {
                kf[c][j] = bf2f((unsigned short)ku[j]);
                k2 += kf[c][j] * kf[c][j];
            }
        }
        #pragma unroll
        for (int m = 32; m; m >>= 1) k2 += __shfl_xor(k2, m, 64);
        const float rk = rsqrtf(k2);

        #pragma unroll
        for (int c = 0; c < 2; c++) {
            short8 vu = *(const short8*)&qkv[base + 2048 + c * 512 + lane * 8];
            #pragma unroll
            for (int j = 0; j < 8; j++)
                a[c][j] += kf[c][j] * rk * bf2f((unsigned short)vu[j]);
        }
    }
    #pragma unroll
    for (int c = 0; c < 2; c++) {
        *(float4*)&kvbuf[wv][c * 512 + lane * 8]     = make_float4(a[c][0], a[c][1], a[c][2], a[c][3]);
        *(float4*)&kvbuf[wv][c * 512 + lane * 8 + 4] = make_float4(a[c][4], a[c][5], a[c][6], a[c][7]);
    }
    __syncthreads();
    float4 s = *(const float4*)&kvbuf[0][tid * 4];
    #pragma unroll
    for (int w = 1; w < 4; w++) {
        float4 t = *(const float4*)&kvbuf[w][tid * 4];
        s.x += t.x; s.y += t.y; s.z += t.z; s.w += t.w;
    }
    *(float4*)&part[(size_t)blockIdx.x * 1024 + tid * 4] = s;
}

// ---------- fused reduce + scale_w (NO cross-block dependency) ----------
// 128 blocks: b = bid>>5, 32 k-cols kc0 = (bid&31)*32. Phase A: reduce 256
// partials for those cols into LDS. Phase B: write WoutS[b][n][kc0..kc0+32)
// for all 1024 n rows (kv never round-trips through global).
__global__ __launch_bounds__(256) void reduce_scale(const float* __restrict__ part,
                                                    const unsigned short* __restrict__ WoutT,
                                                    unsigned short* __restrict__ WoutS) {
    __shared__ float red[8][32];
    __shared__ float kvs[32];
    const int b   = blockIdx.x >> 5;
    const int kc0 = (blockIdx.x & 31) * 32;
    const int col = kc0 + (threadIdx.x & 31);
    const int g   = threadIdx.x >> 5;    // 0..7
    float s = 0.f;
    #pragma unroll 4
    for (int r = g * 32; r < g * 32 + 32; r++)
        s += part[(size_t)(b * 256 + r) * 1024 + col];
    red[g][threadIdx.x & 31] = s;
    __syncthreads();
    if (g == 0) {
        float t = 0.f;
        #pragma unroll
        for (int w = 0; w < 8; w++) t += red[w][threadIdx.x & 31];
        kvs[threadIdx.x & 31] = t;
    }
    __syncthreads();

    const int kh = (threadIdx.x & 3) * 8;
    float kvv[8];
    #pragma unroll
    for (int q = 0; q < 8; q++) kvv[q] = kvs[kh + q];
    const unsigned short* src = WoutT + kc0 + kh;
    unsigned short* dst = WoutS + ((size_t)b << 20) + kc0 + kh;
    #pragma unroll
    for (int i = 0; i < 16; i++) {
        const int n = (threadIdx.x >> 2) + i * 64;
        short8 w = *(const short8*)&src[n * 1024];
        short8 o;
        #pragma unroll
        for (int q = 0; q < 8; q++)
            o[q] = (short)f2bf(bf2f((unsigned short)w[q]) * kvv[q]);
        *(short8*)&dst[n * 1024] = o;
    }
}

extern "C" void kernel_launch(void* const* d_in, const int* in_sizes, int n_in,
                              void* d_out, int out_size, void* d_ws, size_t ws_size,
                              hipStream_t stream) {
    const float* x    = (const float*)d_in[0];   // (4,4096,1024)
    const float* Wqkv = (const float*)d_in[1];   // (1024,3072)
    const float* bqkv = (const float*)d_in[2];   // (3072)
    const float* Wout = (const float*)d_in[3];   // (1024,1024)
    const float* bout = (const float*)d_in[4];   // (1024)
    float* out = (float*)d_out;                  // (4,4096,1024) fp32

    // workspace layout (all offsets within the known-safe ~136 MB footprint)
    char* ws = (char*)d_ws;
    unsigned short* x_bf  = (unsigned short*)(ws + 0);           // 32 MB (dead after GEMM1)
    unsigned short* WqkvT = (unsigned short*)(ws + 33554432);    // 6 MB
    unsigned short* WoutT = (unsigned short*)(ws + 39845888);    // 2 MB
    unsigned short* qkv   = (unsigned short*)(ws + 41943040);    // 96 MB
    float* q2sum          = (float*)(ws + 142606336);            // 64 KB (old rnq slot)
    float* part           = (float*)(ws + 0);                    // 4 MB (x_bf region, dead)
    unsigned short* WoutS = (unsigned short*)(ws + 8388608);     // 8 MB (x_bf region, dead)

    // fused: x conversion + both weight transposes
    prep<<<12288, 256, 0, stream>>>(x, Wqkv, Wout, x_bf, WqkvT, WoutT);

    hipMemsetAsync(q2sum, 0, 16384 * sizeof(float), stream);

    // qkv = x @ Wqkv + bqkv (M=16384, N=3072, K=1024) -> bf16; also q2 partials
    gemm_bf16<true><<<768, 512, 0, stream>>>(x_bf, 1024, WqkvT, 1024, bqkv,
                                             nullptr, q2sum,
                                             (void*)qkv, 3072, 1024, 12, 0);

    norm_kv<<<1024, 256, 0, stream>>>(qkv, part);

    // fold kv into Wout per batch (reduce + scale in one launch)
    reduce_scale<<<128, 256, 0, stream>>>(part, WoutT, WoutS);

    // y[b] = rsqrt(q2) * (q[b] @ (Wout .* kv[b])) + bout -> fp32
    gemm_bf16<false><<<256, 512, 0, stream>>>(qkv, 3072, WoutS, 1024, bout,
                                              q2sum, nullptr,
                                              (void*)out, 1024, 1024, 4, 1 << 20);
}

// Round 12
// 304.038 us; speedup vs baseline: 1.7736x; 1.0138x over previous
//
#include <hip/hip_runtime.h>

// ---------- types / helpers ----------
typedef __attribute__((ext_vector_type(8))) short short8;   // 8 bf16 = 4 VGPRs
typedef __attribute__((ext_vector_type(4))) float f32x4;

__device__ __forceinline__ float bf2f(unsigned short u) {
    union { unsigned int i; float f; } x; x.i = ((unsigned int)u) << 16; return x.f;
}
__device__ __forceinline__ unsigned short f2bf(float f) {
    union { float f; unsigned int i; } x; x.f = f;
    unsigned int r = x.i + 0x7fffu + ((x.i >> 16) & 1u);   // RTNE
    return (unsigned short)(r >> 16);
}
__device__ __forceinline__ void async_copy16(const void* g, void* l) {
    __builtin_amdgcn_global_load_lds(
        (const __attribute__((address_space(1))) void*)g,
        (__attribute__((address_space(3))) void*)l,
        16, 0, 0);
}

// ---------- fused prep: x fp32->bf16 (blocks 0..8191), Wqkv^T (8192..11263),
// ---------- Wout^T (11264..12287).
__global__ __launch_bounds__(256) void prep(const float* __restrict__ x,
                                            const float* __restrict__ Wqkv,
                                            const float* __restrict__ Wout,
                                            unsigned short* __restrict__ x_bf,
                                            unsigned short* __restrict__ WqkvT,
                                            unsigned short* __restrict__ WoutT) {
    __shared__ float tile[32][33];
    const int blk = blockIdx.x;
    if (blk < 8192) {
        const size_t i = ((size_t)blk * 256 + threadIdx.x) * 8;
        float4 v0 = *(const float4*)&x[i];
        float4 v1 = *(const float4*)&x[i + 4];
        short8 o;
        o[0] = (short)f2bf(v0.x); o[1] = (short)f2bf(v0.y);
        o[2] = (short)f2bf(v0.z); o[3] = (short)f2bf(v0.w);
        o[4] = (short)f2bf(v1.x); o[5] = (short)f2bf(v1.y);
        o[6] = (short)f2bf(v1.z); o[7] = (short)f2bf(v1.w);
        *(short8*)&x_bf[i] = o;
        return;
    }
    const float* in;
    unsigned short* out;
    int R, C, idx;
    if (blk < 11264) { in = Wqkv; out = WqkvT; R = 1024; C = 3072; idx = blk - 8192; }
    else             { in = Wout; out = WoutT; R = 1024; C = 1024; idx = blk - 11264; }
    const int nbx = C / 32;
    const int bx = (idx % nbx) * 32;
    const int by = (idx / nbx) * 32;
    const int tx = threadIdx.x & 31, ty = threadIdx.x >> 5;
    #pragma unroll
    for (int r = ty; r < 32; r += 8)
        tile[r][tx] = in[(size_t)(by + r) * C + bx + tx];
    __syncthreads();
    #pragma unroll
    for (int r = ty; r < 32; r += 8)
        out[(size_t)(bx + r) * R + by + tx] = f2bf(tile[tx][r]);
}

// ---------- bf16 GEMM: C[M,N] = A[M,K] * Bt[N,K]^T + bias ----------
// K-loop FROZEN (R4/R7): 256x256 tile, BK=64, 512 threads (8 waves 2x4),
// quadrant phases {12,4,8,0} ds_reads, vmcnt(6)@ph4.
// Round-12: XCD swizzle reverted to the R7 bijective mapping (R11's 16m x 6n
// remap cut FETCH 94.5->74 MB but cost +7 us — traffic != time; latency
// hypothesis dead). KEEPS R11's q2-fold: GEMM1 epilogue computes per-row
// sum-of-squares of rounded q (n0<1024 blocks) -> q2out; GEMM2 epilogue
// applies rsqrtf(q2[row]).
template<bool OUT_BF16>
__global__ __launch_bounds__(512, 2) void gemm_bf16(const unsigned short* __restrict__ A, int lda,
                                                    const unsigned short* __restrict__ Bt, int ldb,
                                                    const float* __restrict__ bias,
                                                    const float* __restrict__ rq,
                                                    float* __restrict__ q2out,
                                                    void* __restrict__ C, int ldc, int K, int ntn,
                                                    int bstride) {
    __shared__ short smem[65536];   // 128 KiB

    const int tid  = threadIdx.x;
    const int lane = tid & 63;
    const int quad = lane >> 4;
    const int l16  = lane & 15;
    const int wid  = tid >> 6;
    const int wm   = wid >> 2;       // 0..1
    const int wn   = wid & 3;        // 0..3

    // XCD-aware bijective blockIdx swizzle (grids are % 8 == 0) — R7-proven.
    const int nwg = gridDim.x;
    const int bid = blockIdx.x;
    const int wg  = (bid & 7) * (nwg >> 3) + (bid >> 3);
    const int m0  = (wg / ntn) * 256;
    const int n0  = (wg % ntn) * 256;

    Bt += (size_t)(m0 >> 12) * (size_t)bstride;   // per-batch B panel (0 for GEMM1)

    const int NT = K >> 6;           // K-tiles (16 for K=1024); must be even >= 4

    // ---- hoisted LDS read bases (shorts). Swizzle chunk SW = quad ^ ((l16>>1)&3).
    const int SW8  = (quad ^ ((l16 >> 1) & 3)) * 8;
    const int offA = (wm * 128 + l16) * 32 + SW8;
    const int offB = 16384 + (wn * 64 + l16) * 32 + SW8;
    const short* pA0 = smem + offA;
    const short* pA1 = smem + 32768 + offA;
    const short* pB0 = smem + offB;
    const short* pB1 = smem + 32768 + offB;

    // ---- staging source pointers (advance by 64 shorts per K-tile, 128 per pair)
    const unsigned short *aS0, *aS1, *bS0, *bS1;
    {
        const int L0  = tid,        r0 = L0 >> 2, c0 = (L0 & 3) ^ ((r0 >> 1) & 3);
        const int L1  = 512 + tid,  r1 = L1 >> 2, c1 = (L1 & 3) ^ ((r1 >> 1) & 3);
        aS0 = A  + (size_t)(m0 + r0) * lda + c0 * 8;
        aS1 = A  + (size_t)(m0 + r1) * lda + c1 * 8;
        bS0 = Bt + (size_t)(n0 + r0) * ldb + c0 * 8;
        bS1 = Bt + (size_t)(n0 + r1) * ldb + c1 * 8;
    }
    const int dstoff = tid * 8;      // shorts (lane x 16B, linear gload_lds dest)

#define STAGE(BUF, ISB, H, AH) do { \
        short* d_ = smem + (BUF) * 32768 + (ISB) * 16384 + (H) * 8192 + dstoff; \
        async_copy16(((ISB) ? bS0 : aS0) + (AH) * 64 + (H) * 32, d_); \
        async_copy16(((ISB) ? bS1 : aS1) + (AH) * 64 + (H) * 32, d_ + 4096); \
    } while (0)

#define RDA4(dst, P, H, IB) do { \
        dst[0] = *(const short8*)(pA##P + ((IB) + 0) * 512 + (H) * 8192); \
        dst[1] = *(const short8*)(pA##P + ((IB) + 1) * 512 + (H) * 8192); \
        dst[2] = *(const short8*)(pA##P + ((IB) + 2) * 512 + (H) * 8192); \
        dst[3] = *(const short8*)(pA##P + ((IB) + 3) * 512 + (H) * 8192); \
    } while (0)
#define RDB2(dst, P, H, JB) do { \
        dst[0] = *(const short8*)(pB##P + ((JB) + 0) * 512 + (H) * 8192); \
        dst[1] = *(const short8*)(pB##P + ((JB) + 1) * 512 + (H) * 8192); \
    } while (0)

#define MFMA_Q(IB, JB, ak0, ak1, bk0, bk1) do { \
        _Pragma("unroll") \
        for (int i_ = 0; i_ < 4; i_++) \
            _Pragma("unroll") \
            for (int j_ = 0; j_ < 2; j_++) \
                acc[(IB) + i_][(JB) + j_] = __builtin_amdgcn_mfma_f32_16x16x32_bf16(ak0[i_], bk0[j_], acc[(IB) + i_][(JB) + j_], 0, 0, 0); \
        _Pragma("unroll") \
        for (int i_ = 0; i_ < 4; i_++) \
            _Pragma("unroll") \
            for (int j_ = 0; j_ < 2; j_++) \
                acc[(IB) + i_][(JB) + j_] = __builtin_amdgcn_mfma_f32_16x16x32_bf16(ak1[i_], bk1[j_], acc[(IB) + i_][(JB) + j_], 0, 0, 0); \
    } while (0)

#define PH_MID() do { \
        __builtin_amdgcn_s_barrier(); \
        __builtin_amdgcn_s_setprio(1); \
    } while (0)
#define PH_END() do { \
        __builtin_amdgcn_s_setprio(0); \
        __builtin_amdgcn_s_barrier(); \
    } while (0)

#define VM6   asm volatile("s_waitcnt vmcnt(6)" ::: "memory")
#define VM0   asm volatile("s_waitcnt vmcnt(0)" ::: "memory")
#define VMNOP ((void)0)

#define KTILE(P, AH, T1, T2, VMW) do { \
        short8 a0k0[4], a0k1[4], a1k0[4], a1k1[4]; \
        short8 b0k0[2], b0k1[2], b1k0[2], b1k1[2]; \
        RDA4(a0k0, P, 0, 0); RDA4(a0k1, P, 1, 0); \
        RDB2(b0k0, P, 0, 0); RDB2(b0k1, P, 1, 0); \
        if (T1) STAGE((P) ^ 1, 1, 1, (AH) + 1); \
        PH_MID(); MFMA_Q(0, 0, a0k0, a0k1, b0k0, b0k1); PH_END(); \
        RDB2(b1k0, P, 0, 2); RDB2(b1k1, P, 1, 2); \
        if (T2) STAGE(P, 1, 0, (AH) + 2); \
        PH_MID(); MFMA_Q(0, 2, a0k0, a0k1, b1k0, b1k1); PH_END(); \
        RDA4(a1k0, P, 0, 4); RDA4(a1k1, P, 1, 4); \
        if (T2) STAGE(P, 0, 0, (AH) + 2); \
        PH_MID(); MFMA_Q(4, 2, a1k0, a1k1, b1k0, b1k1); PH_END(); \
        if (T2) STAGE(P, 0, 1, (AH) + 2); \
        VMW; \
        PH_MID(); MFMA_Q(4, 0, a1k0, a1k1, b0k0, b0k1); PH_END(); \
    } while (0)

    f32x4 acc[8][4] = {};

    // ---- prologue: tile0 {A0,B0,A1,B1}; tile1 {B0,A0,A1}
    STAGE(0, 0, 0, 0); STAGE(0, 1, 0, 0); STAGE(0, 0, 1, 0); STAGE(0, 1, 1, 0);
    asm volatile("s_waitcnt vmcnt(4)" ::: "memory");
    STAGE(1, 1, 0, 1); STAGE(1, 0, 0, 1); STAGE(1, 0, 1, 1);
    asm volatile("s_waitcnt vmcnt(6)" ::: "memory");
    __builtin_amdgcn_s_barrier();

    for (int u = 0; u + 3 < NT; u += 2) {
        KTILE(0, 0, 1, 1, VM6);
        KTILE(1, 1, 1, 1, VM6);
        aS0 += 128; aS1 += 128; bS0 += 128; bS1 += 128;
    }
    KTILE(0, 0, 1, 0, VM0);
    KTILE(1, 1, 0, 0, VMNOP);

    // ---- epilogue. C/D layout: col = lane&15, row = quad*4 + r  [m89/m91]
    if (OUT_BF16) {
        const bool doq2 = (q2out != nullptr) && (n0 < 1024);   // q-region blocks
        __syncthreads();                               // full drain; reuse smem
        unsigned short* tile = (unsigned short*)smem;  // [128][264] padded
        unsigned short* Cp   = (unsigned short*)C;
        #pragma unroll
        for (int hm = 0; hm < 2; hm++) {
            if (wm == hm) {
                #pragma unroll
                for (int j = 0; j < 4; j++) {
                    const int tcol = wn * 64 + j * 16 + l16;
                    const float bv = bias[n0 + tcol];
                    #pragma unroll
                    for (int i = 0; i < 8; i++) {
                        const int trow = i * 16 + quad * 4;
                        #pragma unroll
                        for (int r = 0; r < 4; r++)
                            tile[(trow + r) * 264 + tcol] = f2bf(acc[i][j][r] + bv);
                    }
                }
            }
            __syncthreads();
            #pragma unroll
            for (int pp = 0; pp < 8; pp++) {
                const int row = pp * 16 + (tid >> 5);
                const int ch  = tid & 31;
                short8 v = *(const short8*)&tile[row * 264 + ch * 8];
                *(short8*)&Cp[(size_t)(m0 + hm * 128 + row) * ldc + n0 + ch * 8] = v;
                if (doq2) {
                    // per-row sum of squares of the ROUNDED q values (matches
                    // the original norm_kv numerics, which read bf16 qkv).
                    float sq = 0.f;
                    #pragma unroll
                    for (int q = 0; q < 8; q++) {
                        float f = bf2f((unsigned short)v[q]);
                        sq += f * f;
                    }
                    #pragma unroll
                    for (int m = 1; m <= 16; m <<= 1) sq += __shfl_xor(sq, m, 64);
                    if (ch == 0) atomicAdd(&q2out[m0 + hm * 128 + row], sq);
                }
            }
            __syncthreads();
        }
    } else {
        // fp32 out: y = rsqrt(q2[row])*acc + bias, LDS-restaged for 1KiB stores.
        __syncthreads();
        float* ftile = (float*)smem;
        float* Cp = (float*)C;
        #pragma unroll
        for (int hm = 0; hm < 2; hm++) {
            if (wm == hm) {
                #pragma unroll
                for (int j = 0; j < 4; j++) {
                    const int tcol = wn * 64 + j * 16 + l16;
                    const float bv = bias[n0 + tcol];
                    #pragma unroll
                    for (int i = 0; i < 8; i++) {
                        const int trow = i * 16 + quad * 4;
                        const int cs = tcol ^ ((quad & 1) << 4);
                        #pragma unroll
                        for (int r = 0; r < 4; r++) {
                            const float rqv = rsqrtf(rq[m0 + hm * 128 + trow + r]);
                            ftile[(trow + r) * 256 + cs] = acc[i][j][r] * rqv + bv;
                        }
                    }
                }
            }
            __syncthreads();
            #pragma unroll
            for (int p = 0; p < 16; p++) {
                const int row = p * 8 + (tid >> 6);
                const int c4  = (tid & 63) * 4;
                const int cr  = c4 ^ (((row >> 2) & 1) << 4);
                float4 v = *(const float4*)&ftile[row * 256 + cr];
                *(float4*)&Cp[(size_t)(m0 + hm * 128 + row) * ldc + n0 + c4] = v;
            }
            __syncthreads();
        }
    }
#undef STAGE
#undef RDA4
#undef RDB2
#undef MFMA_Q
#undef PH_MID
#undef PH_END
#undef VM6
#undef VM0
#undef VMNOP
#undef KTILE
}

// ---------- k-norm + kv partials (q handled in GEMM1 epilogue) ----------
__global__ __launch_bounds__(256) void norm_kv(const unsigned short* __restrict__ qkv,
                                               float* __restrict__ part) {
    __shared__ float kvbuf[4][1024];   // 16 KB, one slice per wave
    const int tid = threadIdx.x, lane = tid & 63, wv = tid >> 6;
    const int row0 = blockIdx.x * 16 + wv * 4;
    float a[2][8] = {};

    #pragma unroll
    for (int rr = 0; rr < 4; rr++) {
        const size_t base = (size_t)(row0 + rr) * 3072;
        float k2 = 0.f;
        float kf[2][8];
        #pragma unroll
        for (int c = 0; c < 2; c++) {
            short8 ku = *(const short8*)&qkv[base + 1024 + c * 512 + lane * 8];
            #pragma unroll
            for (int j = 0; j < 8; j++) {
                kf[c][j] = bf2f((unsigned short)ku[j]);
                k2 += kf[c][j] * kf[c][j];
            }
        }
        #pragma unroll
        for (int m = 32; m; m >>= 1) k2 += __shfl_xor(k2, m, 64);
        const float rk = rsqrtf(k2);

        #pragma unroll
        for (int c = 0; c < 2; c++) {
            short8 vu = *(const short8*)&qkv[base + 2048 + c * 512 + lane * 8];
            #pragma unroll
            for (int j = 0; j < 8; j++)
                a[c][j] += kf[c][j] * rk * bf2f((unsigned short)vu[j]);
        }
    }
    #pragma unroll
    for (int c = 0; c < 2; c++) {
        *(float4*)&kvbuf[wv][c * 512 + lane * 8]     = make_float4(a[c][0], a[c][1], a[c][2], a[c][3]);
        *(float4*)&kvbuf[wv][c * 512 + lane * 8 + 4] = make_float4(a[c][4], a[c][5], a[c][6], a[c][7]);
    }
    __syncthreads();
    float4 s = *(const float4*)&kvbuf[0][tid * 4];
    #pragma unroll
    for (int w = 1; w < 4; w++) {
        float4 t = *(const float4*)&kvbuf[w][tid * 4];
        s.x += t.x; s.y += t.y; s.z += t.z; s.w += t.w;
    }
    *(float4*)&part[(size_t)blockIdx.x * 1024 + tid * 4] = s;
}

// ---------- fused reduce + scale_w (NO cross-block dependency) ----------
// 128 blocks: b = bid>>5, 32 k-cols kc0 = (bid&31)*32. Phase A: reduce 256
// partials for those cols into LDS. Phase B: write WoutS[b][n][kc0..kc0+32)
// for all 1024 n rows (kv never round-trips through global).
__global__ __launch_bounds__(256) void reduce_scale(const float* __restrict__ part,
                                                    const unsigned short* __restrict__ WoutT,
                                                    unsigned short* __restrict__ WoutS) {
    __shared__ float red[8][32];
    __shared__ float kvs[32];
    const int b   = blockIdx.x >> 5;
    const int kc0 = (blockIdx.x & 31) * 32;
    const int col = kc0 + (threadIdx.x & 31);
    const int g   = threadIdx.x >> 5;    // 0..7
    float s = 0.f;
    #pragma unroll 4
    for (int r = g * 32; r < g * 32 + 32; r++)
        s += part[(size_t)(b * 256 + r) * 1024 + col];
    red[g][threadIdx.x & 31] = s;
    __syncthreads();
    if (g == 0) {
        float t = 0.f;
        #pragma unroll
        for (int w = 0; w < 8; w++) t += red[w][threadIdx.x & 31];
        kvs[threadIdx.x & 31] = t;
    }
    __syncthreads();

    const int kh = (threadIdx.x & 3) * 8;
    float kvv[8];
    #pragma unroll
    for (int q = 0; q < 8; q++) kvv[q] = kvs[kh + q];
    const unsigned short* src = WoutT + kc0 + kh;
    unsigned short* dst = WoutS + ((size_t)b << 20) + kc0 + kh;
    #pragma unroll
    for (int i = 0; i < 16; i++) {
        const int n = (threadIdx.x >> 2) + i * 64;
        short8 w = *(const short8*)&src[n * 1024];
        short8 o;
        #pragma unroll
        for (int q = 0; q < 8; q++)
            o[q] = (short)f2bf(bf2f((unsigned short)w[q]) * kvv[q]);
        *(short8*)&dst[n * 1024] = o;
    }
}

extern "C" void kernel_launch(void* const* d_in, const int* in_sizes, int n_in,
                              void* d_out, int out_size, void* d_ws, size_t ws_size,
                              hipStream_t stream) {
    const float* x    = (const float*)d_in[0];   // (4,4096,1024)
    const float* Wqkv = (const float*)d_in[1];   // (1024,3072)
    const float* bqkv = (const float*)d_in[2];   // (3072)
    const float* Wout = (const float*)d_in[3];   // (1024,1024)
    const float* bout = (const float*)d_in[4];   // (1024)
    float* out = (float*)d_out;                  // (4,4096,1024) fp32

    // workspace layout (all offsets within the known-safe ~136 MB footprint)
    char* ws = (char*)d_ws;
    unsigned short* x_bf  = (unsigned short*)(ws + 0);           // 32 MB (dead after GEMM1)
    unsigned short* WqkvT = (unsigned short*)(ws + 33554432);    // 6 MB
    unsigned short* WoutT = (unsigned short*)(ws + 39845888);    // 2 MB
    unsigned short* qkv   = (unsigned short*)(ws + 41943040);    // 96 MB
    float* q2sum          = (float*)(ws + 142606336);            // 64 KB (old rnq slot)
    float* part           = (float*)(ws + 0);                    // 4 MB (x_bf region, dead)
    unsigned short* WoutS = (unsigned short*)(ws + 8388608);     // 8 MB (x_bf region, dead)

    // fused: x conversion + both weight transposes
    prep<<<12288, 256, 0, stream>>>(x, Wqkv, Wout, x_bf, WqkvT, WoutT);

    hipMemsetAsync(q2sum, 0, 16384 * sizeof(float), stream);

    // qkv = x @ Wqkv + bqkv (M=16384, N=3072, K=1024) -> bf16; also q2 partials
    gemm_bf16<true><<<768, 512, 0, stream>>>(x_bf, 1024, WqkvT, 1024, bqkv,
                                             nullptr, q2sum,
                                             (void*)qkv, 3072, 1024, 12, 0);

    norm_kv<<<1024, 256, 0, stream>>>(qkv, part);

    // fold kv into Wout per batch (reduce + scale in one launch)
    reduce_scale<<<128, 256, 0, stream>>>(part, WoutT, WoutS);

    // y[b] = rsqrt(q2) * (q[b] @ (Wout .* kv[b])) + bout -> fp32
    gemm_bf16<false><<<256, 512, 0, stream>>>(qkv, 3072, WoutS, 1024, bout,
                                              q2sum, nullptr,
                                              (void*)out, 1024, 1024, 4, 1 << 20);
}